// Round 3
// baseline (280.116 us; speedup 1.0000x reference)
//
#include <hip/hip_runtime.h>

// loss = sum_c (sum_spatial(input[c]) - sum_spatial(target[c]))^2 / C^2
// C=128, H=W=512 -> HW=262144 elems/channel, fp32.
//
// R2 lesson: dur was latency-bound (same 101us even when fully L3-resident;
// VGPR=28 -> only ~4 float4 in flight). Fix: UF=8 batched loads -> 16 KB
// in flight per wave.

#define NCH 128
#define HW (512 * 512)
#define BPC 8                          // blocks per channel -> 1024 blocks (4/CU)
#define ELEMS_PER_BLOCK (HW / BPC)     // 32768
#define NTHREADS 256
#define UF 8                           // float4 loads in flight per array

__global__ void zero_ws_kernel(float* __restrict__ ws) {
    ws[threadIdx.x] = 0.0f;
}

__global__ __launch_bounds__(NTHREADS, 4) void chan_diff_sum_kernel(
        const float* __restrict__ inp,
        const float* __restrict__ tgt,
        float* __restrict__ ws) {
    const int bid = blockIdx.x;
    const int ch  = bid >> 3;          // / BPC
    const int blk = bid & (BPC - 1);
    const size_t base = (size_t)ch * HW + (size_t)blk * ELEMS_PER_BLOCK;
    const float4* __restrict__ pi = (const float4*)(inp + base);
    const float4* __restrict__ pt = (const float4*)(tgt + base);

    const int tid = threadIdx.x;
    const int NV = ELEMS_PER_BLOCK / 4;  // 8192 float4 per block per array

    float acc[UF];
    #pragma unroll
    for (int u = 0; u < UF; ++u) acc[u] = 0.0f;

    // 4 superiterations; each issues 16 independent float4 loads (16 KB/wave
    // in flight) before consuming any.
    for (int i = tid; i < NV; i += UF * NTHREADS) {
        float4 va[UF], vb[UF];
        #pragma unroll
        for (int u = 0; u < UF; ++u) va[u] = pi[i + u * NTHREADS];
        #pragma unroll
        for (int u = 0; u < UF; ++u) vb[u] = pt[i + u * NTHREADS];
        #pragma unroll
        for (int u = 0; u < UF; ++u) {
            acc[u] += (va[u].x - vb[u].x) + (va[u].y - vb[u].y)
                    + (va[u].z - vb[u].z) + (va[u].w - vb[u].w);
        }
    }

    float s = 0.0f;
    #pragma unroll
    for (int u = 0; u < UF; ++u) s += acc[u];

    // wave-64 reduce
    #pragma unroll
    for (int off = 32; off > 0; off >>= 1)
        s += __shfl_down(s, off, 64);

    __shared__ float sm[NTHREADS / 64];
    const int wave = tid >> 6;
    const int lane = tid & 63;
    if (lane == 0) sm[wave] = s;
    __syncthreads();
    if (tid == 0) {
        float t = 0.0f;
        #pragma unroll
        for (int w = 0; w < NTHREADS / 64; ++w) t += sm[w];
        atomicAdd(&ws[ch], t);
    }
}

__global__ void finalize_kernel(const float* __restrict__ ws,
                                float* __restrict__ out) {
    const int tid = threadIdx.x;  // 128 threads
    float d = ws[tid];
    float s = d * d;
    #pragma unroll
    for (int off = 32; off > 0; off >>= 1)
        s += __shfl_down(s, off, 64);
    __shared__ float sm[2];
    if ((tid & 63) == 0) sm[tid >> 6] = s;
    __syncthreads();
    if (tid == 0) out[0] = (sm[0] + sm[1]) * (1.0f / (128.0f * 128.0f));
}

extern "C" void kernel_launch(void* const* d_in, const int* in_sizes, int n_in,
                              void* d_out, int out_size, void* d_ws, size_t ws_size,
                              hipStream_t stream) {
    const float* inp = (const float*)d_in[0];
    const float* tgt = (const float*)d_in[1];
    float* out = (float*)d_out;
    float* ws  = (float*)d_ws;   // 128 floats of per-channel diff sums

    zero_ws_kernel<<<1, NCH, 0, stream>>>(ws);
    chan_diff_sum_kernel<<<NCH * BPC, NTHREADS, 0, stream>>>(inp, tgt, ws);
    finalize_kernel<<<1, NCH, 0, stream>>>(ws, out);
}

// Round 4
// 278.859 us; speedup vs baseline: 1.0045x; 1.0045x over previous
//
#include <hip/hip_runtime.h>

// loss = sum_c (sum_spatial(input[c]) - sum_spatial(target[c]))^2 / C^2
// C=128, H=W=512 -> HW=262144 elems/channel, fp32.
//
// R3 lesson: dur is identical whether data is in HBM or fully L3-resident,
// and identical across ILP/occupancy configs -> bound at ~2.6 TB/s by
// power-of-2 aliasing: pi[i] and pt[i] are exactly 2^27 B apart -> same
// HBM channel / L3 slice every access. Fix: separate sum loops (linearity)
// + 32 KB rotation of the tgt stream within each chunk.

#define NCH 128
#define HW (512 * 512)
#define BPC 16                         // blocks per channel -> 2048 blocks (8/CU)
#define ELEMS_PER_BLOCK (HW / BPC)     // 16384 elems = 64 KB per array
#define NTHREADS 256
#define NV (ELEMS_PER_BLOCK / 4)       // 4096 float4 per array per block
#define UF 4
#define ROT (NV / 2)                   // 2048 float4 = 32 KB rotation

__global__ void zero_ws_kernel(float* __restrict__ ws) {
    ws[threadIdx.x] = 0.0f;
}

__global__ __launch_bounds__(NTHREADS) void chan_diff_sum_kernel(
        const float* __restrict__ inp,
        const float* __restrict__ tgt,
        float* __restrict__ ws) {
    const int bid = blockIdx.x;
    const int ch  = bid >> 4;          // / BPC
    const int blk = bid & (BPC - 1);
    const size_t base = (size_t)ch * HW + (size_t)blk * ELEMS_PER_BLOCK;
    const float4* __restrict__ pi = (const float4*)(inp + base);
    const float4* __restrict__ pt = (const float4*)(tgt + base);

    const int tid = threadIdx.x;

    // ---- stream A: sum(inp chunk) ----
    float sa0 = 0.0f, sa1 = 0.0f, sa2 = 0.0f, sa3 = 0.0f;
    for (int i = tid; i < NV; i += UF * NTHREADS) {
        float4 v0 = pi[i + 0 * NTHREADS];
        float4 v1 = pi[i + 1 * NTHREADS];
        float4 v2 = pi[i + 2 * NTHREADS];
        float4 v3 = pi[i + 3 * NTHREADS];
        sa0 += (v0.x + v0.y) + (v0.z + v0.w);
        sa1 += (v1.x + v1.y) + (v1.z + v1.w);
        sa2 += (v2.x + v2.y) + (v2.z + v2.w);
        sa3 += (v3.x + v3.y) + (v3.z + v3.w);
    }

    // ---- stream B: sum(tgt chunk), rotated by 32 KB to break channel alias
    float sb0 = 0.0f, sb1 = 0.0f, sb2 = 0.0f, sb3 = 0.0f;
    for (int i = tid; i < NV; i += UF * NTHREADS) {
        int j0 = i + 0 * NTHREADS + ROT; if (j0 >= NV) j0 -= NV;
        int j1 = i + 1 * NTHREADS + ROT; if (j1 >= NV) j1 -= NV;
        int j2 = i + 2 * NTHREADS + ROT; if (j2 >= NV) j2 -= NV;
        int j3 = i + 3 * NTHREADS + ROT; if (j3 >= NV) j3 -= NV;
        float4 v0 = pt[j0];
        float4 v1 = pt[j1];
        float4 v2 = pt[j2];
        float4 v3 = pt[j3];
        sb0 += (v0.x + v0.y) + (v0.z + v0.w);
        sb1 += (v1.x + v1.y) + (v1.z + v1.w);
        sb2 += (v2.x + v2.y) + (v2.z + v2.w);
        sb3 += (v3.x + v3.y) + (v3.z + v3.w);
    }

    float s = ((sa0 + sa1) + (sa2 + sa3)) - ((sb0 + sb1) + (sb2 + sb3));

    // wave-64 reduce
    #pragma unroll
    for (int off = 32; off > 0; off >>= 1)
        s += __shfl_down(s, off, 64);

    __shared__ float sm[NTHREADS / 64];
    const int wave = tid >> 6;
    const int lane = tid & 63;
    if (lane == 0) sm[wave] = s;
    __syncthreads();
    if (tid == 0) {
        float t = 0.0f;
        #pragma unroll
        for (int w = 0; w < NTHREADS / 64; ++w) t += sm[w];
        atomicAdd(&ws[ch], t);
    }
}

__global__ void finalize_kernel(const float* __restrict__ ws,
                                float* __restrict__ out) {
    const int tid = threadIdx.x;  // 128 threads
    float d = ws[tid];
    float s = d * d;
    #pragma unroll
    for (int off = 32; off > 0; off >>= 1)
        s += __shfl_down(s, off, 64);
    __shared__ float sm[2];
    if ((tid & 63) == 0) sm[tid >> 6] = s;
    __syncthreads();
    if (tid == 0) out[0] = (sm[0] + sm[1]) * (1.0f / (128.0f * 128.0f));
}

extern "C" void kernel_launch(void* const* d_in, const int* in_sizes, int n_in,
                              void* d_out, int out_size, void* d_ws, size_t ws_size,
                              hipStream_t stream) {
    const float* inp = (const float*)d_in[0];
    const float* tgt = (const float*)d_in[1];
    float* out = (float*)d_out;
    float* ws  = (float*)d_ws;   // 128 floats of per-channel diff sums

    zero_ws_kernel<<<1, NCH, 0, stream>>>(ws);
    chan_diff_sum_kernel<<<NCH * BPC, NTHREADS, 0, stream>>>(inp, tgt, ws);
    finalize_kernel<<<1, NCH, 0, stream>>>(ws, out);
}

// Round 7
// 247.323 us; speedup vs baseline: 1.1326x; 1.1275x over previous
//
#include <hip/hip_runtime.h>

// loss = sum_c (sum_spatial(input[c]) - sum_spatial(target[c]))^2 / C^2
// C=128, H=W=512 -> HW=262144 elems/channel, fp32. 268 MB read total.
//
// R4 ledger: dur pinned 101-104us across {BPC 8/16, UF 2/4/8, paired vs
// separate streams, +rotation, occupancy 35% vs 60%} -> read BW ceiling
// ~2.6 TB/s, NOT latency-bound. FETCH is always exactly one array (134 MB);
// other array is L3-hit (restore just dirtied L3).
// R5/R6 slots were infra timeouts; this is the same NT-load probe:
// nontemporal loads (nt bit) -> don't allocate/evict in L2/L3, avoid
// fighting the restore-dirtied cache. No atomics, no zero_ws kernel
// (unique partial slot per block).

#define NCH 128
#define HW (512 * 512)
#define BPC 16                         // blocks per channel -> 2048 blocks
#define ELEMS_PER_BLOCK (HW / BPC)     // 16384 elems = 64 KB per array
#define NTHREADS 256
#define NV (ELEMS_PER_BLOCK / 4)       // 4096 float4 per array per block
#define UF 4

typedef float f32x4 __attribute__((ext_vector_type(4)));

__global__ __launch_bounds__(NTHREADS) void chan_diff_sum_kernel(
        const float* __restrict__ inp,
        const float* __restrict__ tgt,
        float* __restrict__ ws) {
    const int bid = blockIdx.x;
    const int ch  = bid >> 4;          // / BPC
    const int blk = bid & (BPC - 1);
    const size_t base = (size_t)ch * HW + (size_t)blk * ELEMS_PER_BLOCK;
    const f32x4* __restrict__ pi = (const f32x4*)(inp + base);
    const f32x4* __restrict__ pt = (const f32x4*)(tgt + base);

    const int tid = threadIdx.x;

    float s0 = 0.0f, s1 = 0.0f, s2 = 0.0f, s3 = 0.0f;
    for (int i = tid; i < NV; i += UF * NTHREADS) {
        f32x4 a0 = __builtin_nontemporal_load(pi + i + 0 * NTHREADS);
        f32x4 a1 = __builtin_nontemporal_load(pi + i + 1 * NTHREADS);
        f32x4 a2 = __builtin_nontemporal_load(pi + i + 2 * NTHREADS);
        f32x4 a3 = __builtin_nontemporal_load(pi + i + 3 * NTHREADS);
        f32x4 b0 = __builtin_nontemporal_load(pt + i + 0 * NTHREADS);
        f32x4 b1 = __builtin_nontemporal_load(pt + i + 1 * NTHREADS);
        f32x4 b2 = __builtin_nontemporal_load(pt + i + 2 * NTHREADS);
        f32x4 b3 = __builtin_nontemporal_load(pt + i + 3 * NTHREADS);
        s0 += ((a0.x - b0.x) + (a0.y - b0.y)) + ((a0.z - b0.z) + (a0.w - b0.w));
        s1 += ((a1.x - b1.x) + (a1.y - b1.y)) + ((a1.z - b1.z) + (a1.w - b1.w));
        s2 += ((a2.x - b2.x) + (a2.y - b2.y)) + ((a2.z - b2.z) + (a2.w - b2.w));
        s3 += ((a3.x - b3.x) + (a3.y - b3.y)) + ((a3.z - b3.z) + (a3.w - b3.w));
    }

    float s = (s0 + s1) + (s2 + s3);

    // wave-64 reduce
    #pragma unroll
    for (int off = 32; off > 0; off >>= 1)
        s += __shfl_down(s, off, 64);

    __shared__ float sm[NTHREADS / 64];
    const int wave = tid >> 6;
    const int lane = tid & 63;
    if (lane == 0) sm[wave] = s;
    __syncthreads();
    if (tid == 0) {
        float t = 0.0f;
        #pragma unroll
        for (int w = 0; w < NTHREADS / 64; ++w) t += sm[w];
        ws[bid] = t;   // unique slot: no atomic, no pre-zero needed
    }
}

// 128 threads: each sums its channel's 16 partials, squares, reduces.
__global__ void finalize_kernel(const float* __restrict__ ws,
                                float* __restrict__ out) {
    const int tid = threadIdx.x;  // 128 threads = 1 per channel
    float d = 0.0f;
    #pragma unroll
    for (int k = 0; k < BPC; ++k) d += ws[tid * BPC + k];
    float s = d * d;
    #pragma unroll
    for (int off = 32; off > 0; off >>= 1)
        s += __shfl_down(s, off, 64);
    __shared__ float sm[2];
    if ((tid & 63) == 0) sm[tid >> 6] = s;
    __syncthreads();
    if (tid == 0) out[0] = (sm[0] + sm[1]) * (1.0f / (128.0f * 128.0f));
}

extern "C" void kernel_launch(void* const* d_in, const int* in_sizes, int n_in,
                              void* d_out, int out_size, void* d_ws, size_t ws_size,
                              hipStream_t stream) {
    const float* inp = (const float*)d_in[0];
    const float* tgt = (const float*)d_in[1];
    float* out = (float*)d_out;
    float* ws  = (float*)d_ws;   // 2048 per-block partial sums

    chan_diff_sum_kernel<<<NCH * BPC, NTHREADS, 0, stream>>>(inp, tgt, ws);
    finalize_kernel<<<1, NCH, 0, stream>>>(ws, out);
}

// Round 15
// 245.578 us; speedup vs baseline: 1.1406x; 1.0071x over previous
//
#include <hip/hip_runtime.h>

// loss = sum_c (sum_spatial(input[c]) - sum_spatial(target[c]))^2 / C^2
// C=128, H=W=512 -> HW=262144 elems/channel, fp32. 268 MB read total.
//
// Ledger: R2-R4 cached loads pinned at ~102us (2.6 TB/s) regardless of
// ILP/occupancy/pairing -> allocation contention vs restore-dirtied L2/L3.
// R7: NT loads -> ~75us inferred (3.6 TB/s), dur 275->247. Harness restore
// overhead inside dur_us ~170us (537 MB fills run at 6.9 TB/s -> chip BW
// is there). R8-R14 slots were infra timeouts; same probe: one array per
// block (no wave mixes the two streams 2^27 B apart), 4096 blocks, NT
// dwordx4.

#define NCH 128
#define HW (512 * 512)
#define BPC 16                         // chunks per channel per array
#define ELEMS_PER_BLOCK (HW / BPC)     // 16384 elems = 64 KB
#define NTHREADS 256
#define NV (ELEMS_PER_BLOCK / 4)       // 4096 float4 per chunk
#define UF 4
#define NCHUNK (NCH * BPC)             // 2048 chunks per array

typedef float f32x4 __attribute__((ext_vector_type(4)));

__global__ __launch_bounds__(NTHREADS) void chan_sum_kernel(
        const float* __restrict__ inp,
        const float* __restrict__ tgt,
        float* __restrict__ ws) {
    const int bid = blockIdx.x;              // 0..4095
    const int cb  = bid & (NCHUNK - 1);      // chunk id within array
    const float* __restrict__ src = (bid < NCHUNK) ? inp : tgt;
    const int ch  = cb >> 4;                 // / BPC
    const int blk = cb & (BPC - 1);
    const size_t base = (size_t)ch * HW + (size_t)blk * ELEMS_PER_BLOCK;
    const f32x4* __restrict__ p = (const f32x4*)(src + base);

    const int tid = threadIdx.x;

    float s0 = 0.0f, s1 = 0.0f, s2 = 0.0f, s3 = 0.0f;
    for (int i = tid; i < NV; i += UF * NTHREADS) {
        f32x4 v0 = __builtin_nontemporal_load(p + i + 0 * NTHREADS);
        f32x4 v1 = __builtin_nontemporal_load(p + i + 1 * NTHREADS);
        f32x4 v2 = __builtin_nontemporal_load(p + i + 2 * NTHREADS);
        f32x4 v3 = __builtin_nontemporal_load(p + i + 3 * NTHREADS);
        s0 += (v0.x + v0.y) + (v0.z + v0.w);
        s1 += (v1.x + v1.y) + (v1.z + v1.w);
        s2 += (v2.x + v2.y) + (v2.z + v2.w);
        s3 += (v3.x + v3.y) + (v3.z + v3.w);
    }

    float s = (s0 + s1) + (s2 + s3);

    // wave-64 reduce
    #pragma unroll
    for (int off = 32; off > 0; off >>= 1)
        s += __shfl_down(s, off, 64);

    __shared__ float sm[NTHREADS / 64];
    const int wave = tid >> 6;
    const int lane = tid & 63;
    if (lane == 0) sm[wave] = s;
    __syncthreads();
    if (tid == 0) {
        float t = 0.0f;
        #pragma unroll
        for (int w = 0; w < NTHREADS / 64; ++w) t += sm[w];
        ws[bid] = t;   // unique slot: no atomic, no pre-zero needed
    }
}

// 128 threads: each channel sums 16 inp-partials minus 16 tgt-partials,
// squares, reduces.
__global__ void finalize_kernel(const float* __restrict__ ws,
                                float* __restrict__ out) {
    const int tid = threadIdx.x;  // 128 threads = 1 per channel
    float d = 0.0f;
    #pragma unroll
    for (int k = 0; k < BPC; ++k)
        d += ws[tid * BPC + k] - ws[NCHUNK + tid * BPC + k];
    float s = d * d;
    #pragma unroll
    for (int off = 32; off > 0; off >>= 1)
        s += __shfl_down(s, off, 64);
    __shared__ float sm[2];
    if ((tid & 63) == 0) sm[tid >> 6] = s;
    __syncthreads();
    if (tid == 0) out[0] = (sm[0] + sm[1]) * (1.0f / (128.0f * 128.0f));
}

extern "C" void kernel_launch(void* const* d_in, const int* in_sizes, int n_in,
                              void* d_out, int out_size, void* d_ws, size_t ws_size,
                              hipStream_t stream) {
    const float* inp = (const float*)d_in[0];
    const float* tgt = (const float*)d_in[1];
    float* out = (float*)d_out;
    float* ws  = (float*)d_ws;   // 4096 per-block partial sums

    chan_sum_kernel<<<2 * NCHUNK, NTHREADS, 0, stream>>>(inp, tgt, ws);
    finalize_kernel<<<1, NCH, 0, stream>>>(ws, out);
}